// Round 6
// baseline (245.790 us; speedup 1.0000x reference)
//
#include <hip/hip_runtime.h>

typedef __attribute__((ext_vector_type(4))) float  f32x4;
typedef __attribute__((ext_vector_type(4))) short  s16x4;
typedef __attribute__((ext_vector_type(8))) short  s16x8;
typedef __bf16 bf16x8 __attribute__((ext_vector_type(8)));

#define NBATCH 16
#define SEQ    4096
#define KIN    256
#define HY     64
#define HOUT   512
#define NROWS  (NBATCH*SEQ)   /* 65536 */
#define LC     32
#define NC     (SEQ/LC)       /* 128 */

static __device__ __forceinline__ short f2bf(float f) {
  unsigned u = __float_as_uint(f);
  u = u + 0x7FFF + ((u >> 16) & 1);          // RNE
  return (short)(u >> 16);
}
static __device__ __forceinline__ float bf2f(short h) {
  return __uint_as_float(((unsigned)(unsigned short)h) << 16);
}
static __device__ __forceinline__ f32x4 mfma16(bf16x8 a, bf16x8 b, f32x4 c) {
  return __builtin_amdgcn_mfma_f32_16x16x32_bf16(a, b, c, 0, 0, 0);
}
static __device__ __forceinline__ bf16x8 ldfrag(const short* p) {
  return *reinterpret_cast<const bf16x8*>(p);
}
static __device__ __forceinline__ float fsigmoid(float z) {
  return 1.f / (1.f + __expf(-z));
}

// ---------------- weight prep
__global__ void prep_w(const float* __restrict__ lin0W, const float* __restrict__ sig0W,
                       const float* __restrict__ fchW,  const float* __restrict__ fc2W,
                       short* __restrict__ W1h, short* __restrict__ W1l, short* __restrict__ W2h,
                       short* __restrict__ Fh,  short* __restrict__ F2h) {
  int i = blockIdx.x * 256 + threadIdx.x;
  if (i < 16384) {
    float v = lin0W[i]; short h = f2bf(v);
    W1h[i] = h; W1l[i] = f2bf(v - bf2f(h));
    W2h[i] = f2bf(sig0W[i]);
  } else if (i < 16384 + 32768) {
    int j = i - 16384;
    Fh[j] = f2bf(fchW[j]);
  } else if (i < 16384 + 32768 + 131072) {
    int j = i - 49152;
    F2h[j] = f2bf(fc2W[j]);
  }
}

// ---------------- g = relu( (x@lin0^T+b) * sigmoid(x@sig0^T+b) ), bf16 out; also emits xh (bf16 x)
__global__ __launch_bounds__(256) void gemm_g(
    const float* __restrict__ x,
    const short* __restrict__ W1h, const short* __restrict__ W1l, const short* __restrict__ W2h,
    const float* __restrict__ lin0b, const float* __restrict__ sig0b,
    short* __restrict__ Gh, short* __restrict__ xh) {
  __shared__ short Ah[64 * 256];
  __shared__ short Al[64 * 256];
  int tid = threadIdx.x;
  int row0 = blockIdx.x * 64;
  #pragma unroll
  for (int i = 0; i < 16; ++i) {
    int f4 = tid + i * 256;
    int r = f4 >> 6;
    int k = (f4 & 63) << 2;
    f32x4 v = *reinterpret_cast<const f32x4*>(x + (size_t)(row0 + r) * KIN + k);
    s16x4 hh, ll;
    #pragma unroll
    for (int j = 0; j < 4; ++j) {
      short hb = f2bf(v[j]);
      hh[j] = hb;
      ll[j] = f2bf(v[j] - bf2f(hb));
    }
    int sidx = (r * 256 + k) ^ ((r & 7) << 3);
    *reinterpret_cast<s16x4*>(&Ah[sidx]) = hh;
    *reinterpret_cast<s16x4*>(&Al[sidx]) = ll;
    *reinterpret_cast<s16x4*>(xh + (size_t)(row0 + r) * KIN + k) = hh;
  }
  __syncthreads();
  int w = tid >> 6, l = tid & 63;
  int lr = l & 15, lg = l >> 4;
  int c = w * 16 + lr;
  f32x4 acc1[4], acc2[4];
  #pragma unroll
  for (int rt = 0; rt < 4; ++rt) { acc1[rt] = (f32x4)0.f; acc2[rt] = (f32x4)0.f; }
  #pragma unroll
  for (int ks = 0; ks < 8; ++ks) {
    int kk = ks * 32 + lg * 8;
    bf16x8 b2 = ldfrag(W2h + c * 256 + kk);
    #pragma unroll
    for (int rt = 0; rt < 4; ++rt) {
      int r = rt * 16 + lr;
      bf16x8 a = ldfrag(&Ah[(r * 256 + kk) ^ ((r & 7) << 3)]);
      acc2[rt] = mfma16(a, b2, acc2[rt]);
    }
  }
  #pragma unroll
  for (int ks = 0; ks < 8; ++ks) {
    int kk = ks * 32 + lg * 8;
    bf16x8 b1h = ldfrag(W1h + c * 256 + kk);
    bf16x8 b1l = ldfrag(W1l + c * 256 + kk);
    #pragma unroll
    for (int rt = 0; rt < 4; ++rt) {
      int r = rt * 16 + lr;
      int si = (r * 256 + kk) ^ ((r & 7) << 3);
      bf16x8 ah = ldfrag(&Ah[si]);
      bf16x8 al = ldfrag(&Al[si]);
      acc1[rt] = mfma16(ah, b1h, acc1[rt]);
      acc1[rt] = mfma16(ah, b1l, acc1[rt]);
      acc1[rt] = mfma16(al, b1h, acc1[rt]);
    }
  }
  float bl = lin0b[c], bs = sig0b[c];
  #pragma unroll
  for (int rt = 0; rt < 4; ++rt) {
    #pragma unroll
    for (int j = 0; j < 4; ++j) {
      int row = row0 + rt * 16 + lg * 4 + j;
      float y1 = acc1[rt][j] + bl;
      float y2 = acc2[rt][j] + bs;
      float g = y1 * fsigmoid(y2);
      g = g > 0.f ? g : 0.f;
      Gh[(size_t)row * HY + c] = f2bf(g);
    }
  }
}

// ---------------- fused b-GEMM + chunk-operator build. b stored BF16, interleaved in d_out:
// fp32 row r of d_out occupies bytes [r*2048, r*2048+2048); bf16 b of row r lives in the upper
// half [r*2048+1024, r*2048+2048) until scan_passB overwrites the row with fp32 h.
// Block = one chunk: 32 rows x 512 cols, 4 waves (wave w = cols [128w,128w+128)).
// LDS = 32KB total: stage (Axh 16K + AG 4K) overlaid by bL (32x512 bf16, XOR-swizzled).
__global__ __launch_bounds__(256) void gemm_scan_b(
    const short* __restrict__ xh, const short* __restrict__ Gh,
    const short* __restrict__ F2h, const short* __restrict__ Fh,
    const float* __restrict__ fchb, const float* __restrict__ fc2b,
    float* __restrict__ outO, float* __restrict__ Cc, float* __restrict__ Sc) {
  __shared__ __align__(16) char smem[32768];
  short* Axh = (short*)smem;             // 32x256 shorts = 16KB (swizzled), K-loop phase
  short* AG  = (short*)(smem + 16384);   // 32x64 shorts  = 4KB  (swizzled), K-loop phase
  short* bL  = (short*)smem;             // 32x512 shorts = 32KB (swizzled), epilogue phase
  short* bB  = (short*)outO;             // global bf16 b, interleaved (see header comment)
  int tid = threadIdx.x;
  int bc = blockIdx.x;                   // batch*NC + chunk
  int row0 = bc * LC;
  // ---- stage A tiles into LDS (swizzled ds_writes)
  #pragma unroll
  for (int i = 0; i < 4; ++i) {
    int slot = i * 256 + tid;            // 1024 slots of 16B over 32x256
    int r = slot >> 5, k8 = slot & 31;
    s16x8 v = *reinterpret_cast<const s16x8*>(xh + (size_t)(row0 + r) * KIN + k8 * 8);
    *reinterpret_cast<s16x8*>(&Axh[(r * 256 + k8 * 8) ^ ((r & 7) << 3)]) = v;
  }
  {
    int r = tid >> 3, k8 = tid & 7;      // 256 slots over 32x64
    s16x8 v = *reinterpret_cast<const s16x8*>(Gh + (size_t)(row0 + r) * HY + k8 * 8);
    *reinterpret_cast<s16x8*>(&AG[(r * 64 + k8 * 8) ^ ((r & 7) << 3)]) = v;
  }
  __syncthreads();
  int w = tid >> 6, l = tid & 63, lr = l & 15, lg = l >> 4;
  f32x4 acc2[2][8], accF[2][8];
  #pragma unroll
  for (int rt = 0; rt < 2; ++rt)
    #pragma unroll
    for (int ct = 0; ct < 8; ++ct) { acc2[rt][ct] = (f32x4)0.f; accF[rt][ct] = (f32x4)0.f; }
  #pragma unroll
  for (int t = 0; t < 10; ++t) {
    bf16x8 Bf[8], Af[2];
    #pragma unroll
    for (int ct = 0; ct < 8; ++ct) {
      int col = w * 128 + ct * 16 + lr;
      Bf[ct] = (t < 8) ? ldfrag(F2h + (size_t)col * KIN + t * 32 + lg * 8)
                       : ldfrag(Fh  + (size_t)col * HY  + (t - 8) * 32 + lg * 8);
    }
    #pragma unroll
    for (int rt = 0; rt < 2; ++rt) {
      int row = rt * 16 + lr;
      Af[rt] = (t < 8) ? ldfrag(&Axh[(row * 256 + t * 32 + lg * 8) ^ ((row & 7) << 3)])
                       : ldfrag(&AG [(row * 64  + (t - 8) * 32 + lg * 8) ^ ((row & 7) << 3)]);
    }
    #pragma unroll
    for (int rt = 0; rt < 2; ++rt)
      #pragma unroll
      for (int ct = 0; ct < 8; ++ct) {
        if (t < 8) acc2[rt][ct] = mfma16(Af[rt], Bf[ct], acc2[rt][ct]);
        else       accF[rt][ct] = mfma16(Af[rt], Bf[ct], accF[rt][ct]);
      }
  }
  __syncthreads();                        // A-stage dead; smem becomes bL
  // ---- epilogue: gate, convert to bf16, deposit in swizzled bL
  #pragma unroll
  for (int ct = 0; ct < 8; ++ct) {
    int col = w * 128 + ct * 16 + lr;
    float bcv = fchb[col], b2c = fc2b[col];
    #pragma unroll
    for (int rt = 0; rt < 2; ++rt)
      #pragma unroll
      for (int j = 0; j < 4; ++j) {
        int tl = rt * 16 + lg * 4 + j;    // C/D: row=(l>>4)*4+reg (m89)
        float bv = (accF[rt][ct][j] + bcv) * fsigmoid(acc2[rt][ct][j] + b2c);
        bL[(tl * HOUT + col) ^ ((tl & 7) << 3)] = f2bf(bv);
      }
  }
  __syncthreads();
  // ---- coalesced global write of the bf16 b-tile (interleaved in d_out rows)
  #pragma unroll
  for (int i = 0; i < 8; ++i) {
    int slot = i * 256 + tid;             // 2048 slots of 16B over 32x512 shorts
    int t = slot >> 6, s8 = slot & 63;
    s16x8 v = *reinterpret_cast<const s16x8*>(&bL[(t * HOUT + s8 * 8) ^ ((t & 7) << 3)]);
    *reinterpret_cast<s16x8*>(bB + (size_t)(row0 + t) * 1024 + 512 + s8 * 8) = v;
  }
  // ---- chunk operator build (wave 0) from bL
  if (w == 0) {
    float C[8], S[8];
    {
      s16x8 v = *reinterpret_cast<const s16x8*>(&bL[(l * 8) ^ 0]);
      #pragma unroll
      for (int i = 0; i < 8; ++i) { S[i] = bf2f(v[i]); C[i] = 0.f; }
    }
    for (int t = 1; t < LC; ++t) {
      s16x8 v = *reinterpret_cast<const s16x8*>(&bL[(t * HOUT + l * 8) ^ ((t & 7) << 3)]);
      float bb[8];
      #pragma unroll
      for (int i = 0; i < 8; ++i) bb[i] = bf2f(v[i]);
      float pC = __shfl(C[7], (l + 63) & 63);
      float pS = __shfl(S[7], (l + 63) & 63);
      #pragma unroll
      for (int i = 7; i >= 1; --i) { C[i] = fmaxf(0.f, bb[i] + C[i - 1]); S[i] = bb[i] + S[i - 1]; }
      C[0] = fmaxf(0.f, bb[0] + pC);
      S[0] = bb[0] + pS;
    }
    float* cp = Cc + (size_t)bc * HOUT + l * 8;
    float* sp = Sc + (size_t)bc * HOUT + l * 8;
    #pragma unroll
    for (int i = 0; i < 8; ++i) { cp[i] = C[i]; sp[i] = S[i]; }
  }
}

// ---------------- combine: sequential over chunks per batch; emits h_in per chunk + last.
__global__ __launch_bounds__(64) void scan_combine(const float* __restrict__ hidden,
                                                   const float* __restrict__ Cc, const float* __restrict__ Sc,
                                                   float* __restrict__ hIn, float* __restrict__ lastOut) {
  int batch = blockIdx.x;
  int l = threadIdx.x;
  float h[8];
  const float* hp = hidden + batch * HOUT + l * 8;
  #pragma unroll
  for (int i = 0; i < 8; ++i) h[i] = hp[i];
  size_t base0 = ((size_t)batch * NC) * HOUT + l * 8;
  f32x4 c0 = *reinterpret_cast<const f32x4*>(Cc + base0);
  f32x4 c1 = *reinterpret_cast<const f32x4*>(Cc + base0 + 4);
  f32x4 s0 = *reinterpret_cast<const f32x4*>(Sc + base0);
  f32x4 s1 = *reinterpret_cast<const f32x4*>(Sc + base0 + 4);
  for (int c = 0; c < NC; ++c) {
    size_t base = base0 + (size_t)c * HOUT;
    f32x4 nc0, nc1, ns0, ns1;
    if (c + 1 < NC) {
      size_t nb = base + HOUT;
      nc0 = *reinterpret_cast<const f32x4*>(Cc + nb);
      nc1 = *reinterpret_cast<const f32x4*>(Cc + nb + 4);
      ns0 = *reinterpret_cast<const f32x4*>(Sc + nb);
      ns1 = *reinterpret_cast<const f32x4*>(Sc + nb + 4);
    }
    #pragma unroll
    for (int i = 0; i < 8; ++i) hIn[base + i] = h[i];
    float hs[8];
    #pragma unroll
    for (int i = 0; i < 8; ++i) hs[i] = __shfl(h[i], (l + 64 - (LC / 8)) & 63);
    #pragma unroll
    for (int i = 0; i < 4; ++i) {
      h[i]     = fmaxf(c0[i], s0[i] + hs[i]);
      h[4 + i] = fmaxf(c1[i], s1[i] + hs[4 + i]);
    }
    c0 = nc0; c1 = nc1; s0 = ns0; s1 = ns1;
  }
  float* lp = lastOut + batch * HOUT + l * 8;
  #pragma unroll
  for (int i = 0; i < 8; ++i) lp[i] = h[i];
}

// ---------------- pass B: replay recurrence within chunk. Reads bf16 b from the upper half of
// each d_out row, overwrites the row with fp32 h. Read-before-write per row, single wave/chunk.
__global__ __launch_bounds__(64) void scan_passB(float* __restrict__ bm, const float* __restrict__ hIn) {
  int bc = blockIdx.x;
  int l = threadIdx.x;
  int row0 = bc * LC;
  const float* hp = hIn + (size_t)bc * HOUT + l * 8;
  float h[8];
  #pragma unroll
  for (int i = 0; i < 8; ++i) h[i] = hp[i];
  const short* bB = (const short*)bm;
  for (int t = 0; t < LC; ++t) {
    s16x8 v = *reinterpret_cast<const s16x8*>(bB + (size_t)(row0 + t) * 1024 + 512 + l * 8);
    float bb[8];
    #pragma unroll
    for (int i = 0; i < 8; ++i) bb[i] = bf2f(v[i]);
    float ph = __shfl(h[7], (l + 63) & 63);
    #pragma unroll
    for (int i = 7; i >= 1; --i) h[i] = fmaxf(0.f, bb[i] + h[i - 1]);
    h[0] = fmaxf(0.f, bb[0] + ph);
    f32x4 o0, o1;
    #pragma unroll
    for (int i = 0; i < 4; ++i) { o0[i] = h[i]; o1[i] = h[4 + i]; }
    float* bt = bm + (size_t)(row0 + t) * HOUT + l * 8;
    *reinterpret_cast<f32x4*>(bt) = o0;
    *reinterpret_cast<f32x4*>(bt + 4) = o1;
  }
}

extern "C" void kernel_launch(void* const* d_in, const int* in_sizes, int n_in,
                              void* d_out, int out_size, void* d_ws, size_t ws_size,
                              hipStream_t stream) {
  (void)in_sizes; (void)n_in; (void)out_size; (void)ws_size;
  const float* x      = (const float*)d_in[0];
  const float* hidden = (const float*)d_in[1];
  const float* lin0W  = (const float*)d_in[2];
  const float* lin0b  = (const float*)d_in[3];
  const float* sig0W  = (const float*)d_in[4];
  const float* sig0b  = (const float*)d_in[5];
  const float* fchW   = (const float*)d_in[6];
  const float* fchb   = (const float*)d_in[7];
  const float* fc2W   = (const float*)d_in[8];
  const float* fc2b   = (const float*)d_in[9];
  float* outO  = (float*)d_out;
  float* lastO = outO + (size_t)NROWS * HOUT;

  char* wsb = (char*)d_ws;
  size_t off = 0;
  auto alloc = [&](size_t bytes) { char* p = wsb + off; off += (bytes + 255) & ~(size_t)255; return p; };
  float* Cc  = (float*)alloc((size_t)NBATCH * NC * HOUT * 4);
  float* Sc  = (float*)alloc((size_t)NBATCH * NC * HOUT * 4);
  float* hIn = (float*)alloc((size_t)NBATCH * NC * HOUT * 4);
  short* W1h = (short*)alloc(HY * KIN * 2);
  short* W1l = (short*)alloc(HY * KIN * 2);
  short* W2h = (short*)alloc(HY * KIN * 2);
  short* Fh  = (short*)alloc(HOUT * HY * 2);
  short* F2h = (short*)alloc(HOUT * KIN * 2);
  short* Gh  = (short*)alloc((size_t)NROWS * HY * 2);
  short* xh  = (short*)alloc((size_t)NROWS * KIN * 2);

  prep_w<<<704, 256, 0, stream>>>(lin0W, sig0W, fchW, fc2W, W1h, W1l, W2h, Fh, F2h);
  gemm_g<<<NROWS / 64, 256, 0, stream>>>(x, W1h, W1l, W2h, lin0b, sig0b, Gh, xh);
  gemm_scan_b<<<NBATCH * NC, 256, 0, stream>>>(xh, Gh, F2h, Fh, fchb, fc2b, outO, Cc, Sc);
  scan_combine<<<NBATCH, 64, 0, stream>>>(hidden, Cc, Sc, hIn, lastO);
  scan_passB<<<NBATCH * NC, 64, 0, stream>>>(outO, hIn);
}

// Round 7
// 190.326 us; speedup vs baseline: 1.2914x; 1.2914x over previous
//
#include <hip/hip_runtime.h>

typedef __attribute__((ext_vector_type(4))) float  f32x4;
typedef __attribute__((ext_vector_type(4))) short  s16x4;
typedef __attribute__((ext_vector_type(8))) short  s16x8;
typedef __bf16 bf16x8 __attribute__((ext_vector_type(8)));

#define NBATCH 16
#define SEQ    4096
#define KIN    256
#define HY     64
#define HOUT   512
#define NROWS  (NBATCH*SEQ)   /* 65536 */
#define LC     32
#define NC     (SEQ/LC)       /* 128 */

static __device__ __forceinline__ short f2bf(float f) {
  unsigned u = __float_as_uint(f);
  u = u + 0x7FFF + ((u >> 16) & 1);          // RNE
  return (short)(u >> 16);
}
static __device__ __forceinline__ float bf2f(short h) {
  return __uint_as_float(((unsigned)(unsigned short)h) << 16);
}
static __device__ __forceinline__ f32x4 mfma16(bf16x8 a, bf16x8 b, f32x4 c) {
  return __builtin_amdgcn_mfma_f32_16x16x32_bf16(a, b, c, 0, 0, 0);
}
static __device__ __forceinline__ bf16x8 ldfrag(const short* p) {
  return *reinterpret_cast<const bf16x8*>(p);
}
static __device__ __forceinline__ float fsigmoid(float z) {
  return 1.f / (1.f + __expf(-z));
}

// ---------------- weight prep (all plain bf16 now)
__global__ void prep_w(const float* __restrict__ lin0W, const float* __restrict__ sig0W,
                       const float* __restrict__ fchW,  const float* __restrict__ fc2W,
                       short* __restrict__ W1h, short* __restrict__ W2h,
                       short* __restrict__ Fh,  short* __restrict__ F2h) {
  int i = blockIdx.x * 256 + threadIdx.x;
  if (i < 16384) {
    W1h[i] = f2bf(lin0W[i]);
    W2h[i] = f2bf(sig0W[i]);
  } else if (i < 16384 + 32768) {
    Fh[i - 16384] = f2bf(fchW[i - 16384]);
  } else if (i < 16384 + 32768 + 131072) {
    F2h[i - 49152] = f2bf(fc2W[i - 49152]);
  }
}

// ---------------- galpha: per 64-row block, from one LDS x-stage compute
//   g     = relu( (x@lin0^T+b) * sigmoid(x@sig0^T+b) )   -> Gh   (bf16, 8MB)
//   alpha = sigmoid( x@fc2^T + b )                        -> AB   (bf16, 67MB)
// Phase 2 runs in 2 passes of 64 cols/wave to keep acc at 64 VGPRs.
__global__ __launch_bounds__(256) void galpha(
    const float* __restrict__ x,
    const short* __restrict__ W1h, const short* __restrict__ W2h,
    const short* __restrict__ F2h,
    const float* __restrict__ lin0b, const float* __restrict__ sig0b,
    const float* __restrict__ fc2b,
    short* __restrict__ Gh, short* __restrict__ AB) {
  __shared__ short Ah[64 * 256];       // 32KB, XOR-swizzled rows
  int tid = threadIdx.x;
  int row0 = blockIdx.x * 64;
  #pragma unroll
  for (int i = 0; i < 16; ++i) {
    int f4 = tid + i * 256;
    int r = f4 >> 6, k = (f4 & 63) << 2;
    f32x4 v = *reinterpret_cast<const f32x4*>(x + (size_t)(row0 + r) * KIN + k);
    s16x4 hh;
    #pragma unroll
    for (int j = 0; j < 4; ++j) hh[j] = f2bf(v[j]);
    *reinterpret_cast<s16x4*>(&Ah[(r * 256 + k) ^ ((r & 7) << 3)]) = hh;
  }
  __syncthreads();
  int w = tid >> 6, l = tid & 63, lr = l & 15, lg = l >> 4;
  // ---- phase 1: y1, y2 -> g (wave owns 16 cols of 64)
  {
    int c = w * 16 + lr;
    f32x4 a1[4], a2[4];
    #pragma unroll
    for (int rt = 0; rt < 4; ++rt) { a1[rt] = (f32x4)0.f; a2[rt] = (f32x4)0.f; }
    #pragma unroll
    for (int ks = 0; ks < 8; ++ks) {
      int kk = ks * 32 + lg * 8;
      bf16x8 b1 = ldfrag(W1h + c * 256 + kk);
      bf16x8 b2 = ldfrag(W2h + c * 256 + kk);
      #pragma unroll
      for (int rt = 0; rt < 4; ++rt) {
        int r = rt * 16 + lr;
        bf16x8 a = ldfrag(&Ah[(r * 256 + kk) ^ ((r & 7) << 3)]);
        a1[rt] = mfma16(a, b1, a1[rt]);
        a2[rt] = mfma16(a, b2, a2[rt]);
      }
    }
    float bl = lin0b[c], bs = sig0b[c];
    #pragma unroll
    for (int rt = 0; rt < 4; ++rt)
      #pragma unroll
      for (int j = 0; j < 4; ++j) {
        int row = row0 + rt * 16 + lg * 4 + j;   // C/D: row=(l>>4)*4+reg (m89)
        float g = (a1[rt][j] + bl) * fsigmoid(a2[rt][j] + bs);
        g = g > 0.f ? g : 0.f;
        Gh[(size_t)row * HY + c] = f2bf(g);
      }
  }
  // ---- phase 2: alpha (wave owns 128 cols, 2 passes x 64)
  #pragma unroll
  for (int p = 0; p < 2; ++p) {
    f32x4 acc[4][4];
    #pragma unroll
    for (int rt = 0; rt < 4; ++rt)
      #pragma unroll
      for (int ct = 0; ct < 4; ++ct) acc[rt][ct] = (f32x4)0.f;
    #pragma unroll
    for (int ks = 0; ks < 8; ++ks) {
      int kk = ks * 32 + lg * 8;
      bf16x8 Bf[4], Af[4];
      #pragma unroll
      for (int ct = 0; ct < 4; ++ct) {
        int col = w * 128 + p * 64 + ct * 16 + lr;
        Bf[ct] = ldfrag(F2h + (size_t)col * KIN + kk);
      }
      #pragma unroll
      for (int rt = 0; rt < 4; ++rt) {
        int r = rt * 16 + lr;
        Af[rt] = ldfrag(&Ah[(r * 256 + kk) ^ ((r & 7) << 3)]);
      }
      #pragma unroll
      for (int rt = 0; rt < 4; ++rt)
        #pragma unroll
        for (int ct = 0; ct < 4; ++ct)
          acc[rt][ct] = mfma16(Af[rt], Bf[ct], acc[rt][ct]);
    }
    #pragma unroll
    for (int ct = 0; ct < 4; ++ct) {
      int col = w * 128 + p * 64 + ct * 16 + lr;
      float b2c = fc2b[col];
      #pragma unroll
      for (int rt = 0; rt < 4; ++rt)
        #pragma unroll
        for (int j = 0; j < 4; ++j) {
          int row = row0 + rt * 16 + lg * 4 + j;
          AB[(size_t)row * HOUT + col] = f2bf(fsigmoid(acc[rt][ct][j] + b2c));
        }
    }
  }
}

// ---------------- bscan: per chunk (32 rows x 512 cols): b = (g@fch^T + bc) * alpha,
// b (bf16) overwrites alpha in AB in place; wave0 builds the chunk max-plus operator (C,S).
// K=64 only: 2 K-steps, Fh is L1/L2-hot. LDS: AG 4KB (stage) overlaid by bL 32KB (epilogue).
__global__ __launch_bounds__(256) void bscan(
    const short* __restrict__ Gh, const short* __restrict__ Fh,
    const float* __restrict__ fchb,
    short* __restrict__ AB,
    float* __restrict__ Cc, float* __restrict__ Sc) {
  __shared__ __align__(16) char smem[32768];
  short* AG = (short*)smem;            // 32x64 shorts, swizzled (K-loop phase)
  short* bL = (short*)smem;            // 32x512 shorts, swizzled (epilogue phase)
  int tid = threadIdx.x;
  int bc = blockIdx.x;                 // batch*NC + chunk
  int row0 = bc * LC;
  {
    int r = tid >> 3, k8 = tid & 7;
    s16x8 v = *reinterpret_cast<const s16x8*>(Gh + (size_t)(row0 + r) * HY + k8 * 8);
    *reinterpret_cast<s16x8*>(&AG[(r * 64 + k8 * 8) ^ ((r & 7) << 3)]) = v;
  }
  __syncthreads();
  int w = tid >> 6, l = tid & 63, lr = l & 15, lg = l >> 4;
  f32x4 acc[2][8];
  #pragma unroll
  for (int rt = 0; rt < 2; ++rt)
    #pragma unroll
    for (int ct = 0; ct < 8; ++ct) acc[rt][ct] = (f32x4)0.f;
  #pragma unroll
  for (int ks = 0; ks < 2; ++ks) {
    int kk = ks * 32 + lg * 8;
    bf16x8 Bf[8], Af[2];
    #pragma unroll
    for (int ct = 0; ct < 8; ++ct) {
      int col = w * 128 + ct * 16 + lr;
      Bf[ct] = ldfrag(Fh + (size_t)col * HY + kk);
    }
    #pragma unroll
    for (int rt = 0; rt < 2; ++rt) {
      int r = rt * 16 + lr;
      Af[rt] = ldfrag(&AG[(r * 64 + kk) ^ ((r & 7) << 3)]);
    }
    #pragma unroll
    for (int rt = 0; rt < 2; ++rt)
      #pragma unroll
      for (int ct = 0; ct < 8; ++ct)
        acc[rt][ct] = mfma16(Af[rt], Bf[ct], acc[rt][ct]);
  }
  // gate with alpha (read from AB before it is overwritten; same block's rows only)
  #pragma unroll
  for (int ct = 0; ct < 8; ++ct) {
    int col = w * 128 + ct * 16 + lr;
    float bcv = fchb[col];
    #pragma unroll
    for (int rt = 0; rt < 2; ++rt)
      #pragma unroll
      for (int j = 0; j < 4; ++j) {
        int row = row0 + rt * 16 + lg * 4 + j;
        float alpha = bf2f(AB[(size_t)row * HOUT + col]);
        acc[rt][ct][j] = (acc[rt][ct][j] + bcv) * alpha;
      }
  }
  __syncthreads();                      // AG reads complete in all waves; smem becomes bL
  #pragma unroll
  for (int ct = 0; ct < 8; ++ct) {
    int col = w * 128 + ct * 16 + lr;
    #pragma unroll
    for (int rt = 0; rt < 2; ++rt)
      #pragma unroll
      for (int j = 0; j < 4; ++j) {
        int tl = rt * 16 + lg * 4 + j;
        bL[(tl * HOUT + col) ^ ((tl & 15) << 3)] = f2bf(acc[rt][ct][j]);
      }
  }
  __syncthreads();
  // coalesced in-place overwrite of AB rows with bf16 b
  #pragma unroll
  for (int i = 0; i < 8; ++i) {
    int slot = i * 256 + tid;           // 2048 x 16B over 32x512 shorts
    int t = slot >> 6, s8 = slot & 63;
    s16x8 v = *reinterpret_cast<const s16x8*>(&bL[(t * HOUT + s8 * 8) ^ ((t & 15) << 3)]);
    *reinterpret_cast<s16x8*>(AB + (size_t)(row0 + t) * HOUT + s8 * 8) = v;
  }
  // chunk operator build (wave 0) straight from LDS
  if (w == 0) {
    float C[8], S[8];
    {
      s16x8 v = *reinterpret_cast<const s16x8*>(&bL[l * 8]);
      #pragma unroll
      for (int i = 0; i < 8; ++i) { S[i] = bf2f(v[i]); C[i] = 0.f; }
    }
    for (int t = 1; t < LC; ++t) {
      s16x8 v = *reinterpret_cast<const s16x8*>(&bL[(t * HOUT + l * 8) ^ ((t & 15) << 3)]);
      float bb[8];
      #pragma unroll
      for (int i = 0; i < 8; ++i) bb[i] = bf2f(v[i]);
      float pC = __shfl(C[7], (l + 63) & 63);
      float pS = __shfl(S[7], (l + 63) & 63);
      #pragma unroll
      for (int i = 7; i >= 1; --i) { C[i] = fmaxf(0.f, bb[i] + C[i - 1]); S[i] = bb[i] + S[i - 1]; }
      C[0] = fmaxf(0.f, bb[0] + pC);
      S[0] = bb[0] + pS;
    }
    float* cp = Cc + (size_t)bc * HOUT + l * 8;
    float* sp = Sc + (size_t)bc * HOUT + l * 8;
    #pragma unroll
    for (int i = 0; i < 8; ++i) { cp[i] = C[i]; sp[i] = S[i]; }
  }
}

// ---------------- combine: sequential over chunks per batch; emits h_in per chunk + last.
__global__ __launch_bounds__(64) void scan_combine(const float* __restrict__ hidden,
                                                   const float* __restrict__ Cc, const float* __restrict__ Sc,
                                                   float* __restrict__ hIn, float* __restrict__ lastOut) {
  int batch = blockIdx.x;
  int l = threadIdx.x;
  float h[8];
  const float* hp = hidden + batch * HOUT + l * 8;
  #pragma unroll
  for (int i = 0; i < 8; ++i) h[i] = hp[i];
  size_t base0 = ((size_t)batch * NC) * HOUT + l * 8;
  f32x4 c0 = *reinterpret_cast<const f32x4*>(Cc + base0);
  f32x4 c1 = *reinterpret_cast<const f32x4*>(Cc + base0 + 4);
  f32x4 s0 = *reinterpret_cast<const f32x4*>(Sc + base0);
  f32x4 s1 = *reinterpret_cast<const f32x4*>(Sc + base0 + 4);
  for (int c = 0; c < NC; ++c) {
    size_t base = base0 + (size_t)c * HOUT;
    f32x4 nc0, nc1, ns0, ns1;
    if (c + 1 < NC) {
      size_t nb = base + HOUT;
      nc0 = *reinterpret_cast<const f32x4*>(Cc + nb);
      nc1 = *reinterpret_cast<const f32x4*>(Cc + nb + 4);
      ns0 = *reinterpret_cast<const f32x4*>(Sc + nb);
      ns1 = *reinterpret_cast<const f32x4*>(Sc + nb + 4);
    }
    #pragma unroll
    for (int i = 0; i < 8; ++i) hIn[base + i] = h[i];
    float hs[8];
    #pragma unroll
    for (int i = 0; i < 8; ++i) hs[i] = __shfl(h[i], (l + 64 - (LC / 8)) & 63);
    #pragma unroll
    for (int i = 0; i < 4; ++i) {
      h[i]     = fmaxf(c0[i], s0[i] + hs[i]);
      h[4 + i] = fmaxf(c1[i], s1[i] + hs[4 + i]);
    }
    c0 = nc0; c1 = nc1; s0 = ns0; s1 = ns1;
  }
  float* lp = lastOut + batch * HOUT + l * 8;
  #pragma unroll
  for (int i = 0; i < 8; ++i) lp[i] = h[i];
}

// ---------------- pass B: replay recurrence from bf16 b (in AB), write fp32 h to d_out.
__global__ __launch_bounds__(64) void scan_passB(const short* __restrict__ bws,
                                                 const float* __restrict__ hIn,
                                                 float* __restrict__ hout) {
  int bc = blockIdx.x;
  int l = threadIdx.x;
  int row0 = bc * LC;
  const float* hp = hIn + (size_t)bc * HOUT + l * 8;
  float h[8];
  #pragma unroll
  for (int i = 0; i < 8; ++i) h[i] = hp[i];
  for (int t = 0; t < LC; ++t) {
    s16x8 v = *reinterpret_cast<const s16x8*>(bws + (size_t)(row0 + t) * HOUT + l * 8);
    float bb[8];
    #pragma unroll
    for (int i = 0; i < 8; ++i) bb[i] = bf2f(v[i]);
    float ph = __shfl(h[7], (l + 63) & 63);
    #pragma unroll
    for (int i = 7; i >= 1; --i) h[i] = fmaxf(0.f, bb[i] + h[i - 1]);
    h[0] = fmaxf(0.f, bb[0] + ph);
    f32x4 o0, o1;
    #pragma unroll
    for (int i = 0; i < 4; ++i) { o0[i] = h[i]; o1[i] = h[4 + i]; }
    float* bt = hout + (size_t)(row0 + t) * HOUT + l * 8;
    *reinterpret_cast<f32x4*>(bt) = o0;
    *reinterpret_cast<f32x4*>(bt + 4) = o1;
  }
}

extern "C" void kernel_launch(void* const* d_in, const int* in_sizes, int n_in,
                              void* d_out, int out_size, void* d_ws, size_t ws_size,
                              hipStream_t stream) {
  (void)in_sizes; (void)n_in; (void)out_size; (void)ws_size;
  const float* x      = (const float*)d_in[0];
  const float* hidden = (const float*)d_in[1];
  const float* lin0W  = (const float*)d_in[2];
  const float* lin0b  = (const float*)d_in[3];
  const float* sig0W  = (const float*)d_in[4];
  const float* sig0b  = (const float*)d_in[5];
  const float* fchW   = (const float*)d_in[6];
  const float* fchb   = (const float*)d_in[7];
  const float* fc2W   = (const float*)d_in[8];
  const float* fc2b   = (const float*)d_in[9];
  float* outO  = (float*)d_out;
  float* lastO = outO + (size_t)NROWS * HOUT;

  char* wsb = (char*)d_ws;
  size_t off = 0;
  auto alloc = [&](size_t bytes) { char* p = wsb + off; off += (bytes + 255) & ~(size_t)255; return p; };
  float* Cc  = (float*)alloc((size_t)NBATCH * NC * HOUT * 4);
  float* Sc  = (float*)alloc((size_t)NBATCH * NC * HOUT * 4);
  float* hIn = (float*)alloc((size_t)NBATCH * NC * HOUT * 4);
  short* W1h = (short*)alloc(HY * KIN * 2);
  short* W2h = (short*)alloc(HY * KIN * 2);
  short* Fh  = (short*)alloc(HOUT * HY * 2);
  short* F2h = (short*)alloc(HOUT * KIN * 2);
  short* Gh  = (short*)alloc((size_t)NROWS * HY * 2);
  short* AB  = (short*)alloc((size_t)NROWS * HOUT * 2);   // alpha, then b (bf16), in place

  prep_w<<<704, 256, 0, stream>>>(lin0W, sig0W, fchW, fc2W, W1h, W2h, Fh, F2h);
  galpha<<<NROWS / 64, 256, 0, stream>>>(x, W1h, W2h, F2h, lin0b, sig0b, fc2b, Gh, AB);
  bscan<<<NBATCH * NC, 256, 0, stream>>>(Gh, Fh, fchb, AB, Cc, Sc);
  scan_combine<<<NBATCH, 64, 0, stream>>>(hidden, Cc, Sc, hIn, lastO);
  scan_passB<<<NBATCH * NC, 64, 0, stream>>>(AB, hIn, outO);
}